// Round 3
// baseline (163.734 us; speedup 1.0000x reference)
//
#include <hip/hip_runtime.h>
#include <math.h>

#define NN 768
#define FF 128
#define VV 64
#define RH 16
#define SPLITK 12
#define SEND_PER_KC 64          // 768 / SPLITK
#define NITER 8                 // SEND_PER_KC / 8 senders per iter
#define KSTEPS 384              // 12288 / 32
#define NT_S 8                  // scalar n-tiles (128/16)
#define NT_V 16                 // vector n-tiles (256/16)

typedef __attribute__((ext_vector_type(8))) short bf16x8_t;
typedef __attribute__((ext_vector_type(4))) float f32x4;

__device__ __forceinline__ float silu_f(float a) {
  return a / (1.0f + __expf(-a));
}

__device__ __forceinline__ unsigned short f2bf(float f) {
  unsigned u = __builtin_bit_cast(unsigned, f);
  unsigned r = (u + 0x7FFFu + ((u >> 16) & 1u)) >> 16;
  return (unsigned short)r;
}

// ---------------------------------------------------------------------------
// init: hs[n] = embed row; hsv[n] = embed @ Wsv[0]; hv = 0
// ---------------------------------------------------------------------------
__global__ __launch_bounds__(192) void init_kernel(
    const float* __restrict__ embed, const float* __restrict__ Wsv0,
    float* __restrict__ hs, float* __restrict__ hsv, float* __restrict__ hv)
{
  const int n = blockIdx.x, t = threadIdx.x;
  hv[n * 192 + t] = 0.0f;
  if (t < FF) hs[n * FF + t] = embed[t];
  if (t < VV) {
    float acc = 0.f;
    #pragma unroll 8
    for (int f = 0; f < FF; ++f) acc += embed[f] * Wsv0[f * VV + t];
    hsv[n * VV + t] = acc;
  }
}

// ---------------------------------------------------------------------------
// prep: build B matrices in MFMA-fragment-major layout (bf16).
// K index k = s*16 + h; fragment for 16x16x32: lane holds 8 contiguous k at
// kk = (lane>>4)*8+e, n = lane&15. Flat: B[((kstep*NT + ntile)*64 + lane)*8+e].
//   Bs[k][f]        = hs[s][f]  * Wr2s[h][f] / 64                 (N=128)
//   Bv[k][d*64+v]   = x[s][d]   * hsv[s][v] * Wr2v[h][v] / 64     (N=192)
//   Bv[k][192+v]    =             hsv[s][v] * Wr2v[h][v] / 64     (N=64)
// thread = (kstep, ntile 0..23, lane); each thread emits one ushort8.
// ---------------------------------------------------------------------------
__global__ __launch_bounds__(256) void prep_kernel(
    const float* __restrict__ hs, const float* __restrict__ hsv,
    const float* __restrict__ x,
    const float* __restrict__ Wr2s,   // [16][128] layer slice
    const float* __restrict__ Wr2v,   // [16][64]  layer slice
    unsigned short* __restrict__ Bs, unsigned short* __restrict__ Bv)
{
  const int gid   = blockIdx.x * 256 + threadIdx.x;
  const int lane  = gid & 63;
  const int tmp   = gid >> 6;
  const int ntile = tmp % 24;
  const int kstep = tmp / 24;
  if (kstep >= KSTEPS) return;
  const int qq = lane >> 4;              // octet index 0..3
  const int s  = kstep * 2 + (qq >> 1);
  const int hb = (qq & 1) * 8;

  bf16x8_t o;
  if (ntile < NT_S) {
    const int f = ntile * 16 + (lane & 15);
    const float hf = hs[s * FF + f] * 0.015625f;
    #pragma unroll
    for (int e = 0; e < 8; ++e)
      o[e] = (short)f2bf(hf * Wr2s[(hb + e) * FF + f]);
    *(bf16x8_t*)&Bs[((size_t)(kstep * NT_S + ntile) * 64 + lane) * 8] = o;
  } else {
    const int nt2 = ntile - NT_S;
    const int n   = nt2 * 16 + (lane & 15);
    int v; float scale;
    if (n < 192) { const int dd = n >> 6; v = n & 63;
                   scale = x[s * 3 + dd] * hsv[s * VV + v] * 0.015625f; }
    else         { v = n - 192; scale = hsv[s * VV + v] * 0.015625f; }
    #pragma unroll
    for (int e = 0; e < 8; ++e)
      o[e] = (short)f2bf(scale * Wr2v[(hb + e) * VV + v]);
    *(bf16x8_t*)&Bv[((size_t)(kstep * NT_V + nt2) * 64 + lane) * 8] = o;
  }
}

// ---------------------------------------------------------------------------
// edge GEMM: grid = 12 M-blocks x {scalar,vector} x SPLITK. 512 threads.
// Per iter (8 senders = 4 ksteps): each thread computes one (r,s) pair's
// rf (scalar block) or g = rf*iv (vector block), writes A fragments to LDS;
// then 8 waves MFMA: scalar wave w owns n-tile w (4 C-tiles), vector wave w
// owns n-tiles 2w,2w+1 (8 C-tiles). Partials written per K-chunk (no atomics).
// ---------------------------------------------------------------------------
__global__ __launch_bounds__(512) void edge_gemm(
    const float* __restrict__ x,
    const unsigned short* __restrict__ Bs,
    const unsigned short* __restrict__ Bv,
    const float* __restrict__ Wr1,    // [16] layer slice
    float* __restrict__ Ps,           // [SPLITK][768][128]
    float* __restrict__ Pv)           // [SPLITK][768][256]
{
  __shared__ unsigned short A_lds[16 * 64 * 8];  // 16 KB: [ks*4+mt][lane][8]

  const int kc = blockIdx.x % SPLITK;
  const int nt = (blockIdx.x / SPLITK) & 1;
  const int mb = blockIdx.x / (2 * SPLITK);
  const int tid  = threadIdx.x;
  const int lane = tid & 63;
  const int w    = tid >> 6;

  float wr1[RH];
  #pragma unroll
  for (int h = 0; h < RH; ++h) wr1[h] = Wr1[h];

  const int r_local = tid & 63;
  const int s_ii    = tid >> 6;
  const int r = mb * 64 + r_local;
  const float xr0 = x[r * 3 + 0], xr1 = x[r * 3 + 1], xr2 = x[r * 3 + 2];

  f32x4 acc[8];
  #pragma unroll
  for (int i = 0; i < 8; ++i) acc[i] = (f32x4){0.f, 0.f, 0.f, 0.f};

  // A-gen LDS targets for this thread
  const int mt_w   = r_local >> 4;
  const int ks_w   = s_ii >> 1;
  const int lane0  = (r_local & 15) + ((s_ii & 1) << 5);

  for (int it = 0; it < NITER; ++it) {
    // ---- A generation: one (r,s) pair per thread ----
    {
      const int s = kc * SEND_PER_KC + it * 8 + s_ii;
      const float vx = x[s * 3 + 0] - xr0;
      const float vy = x[s * 3 + 1] - xr1;
      const float vz = x[s * 3 + 2] - xr2;
      const float dd = sqrtf(vx * vx + vy * vy + vz * vz);
      const float iv = 1.0f / (dd + 1e-8f);
      const float mulf = nt ? iv : 1.0f;
      bf16x8_t o0, o1;
      #pragma unroll
      for (int h = 0; h < 8; ++h)
        o0[h] = (short)f2bf(silu_f(dd * wr1[h]) * mulf);
      #pragma unroll
      for (int h = 8; h < 16; ++h)
        o1[h - 8] = (short)f2bf(silu_f(dd * wr1[h]) * mulf);
      *(bf16x8_t*)&A_lds[((ks_w * 4 + mt_w) * 64 + lane0) * 8]        = o0;
      *(bf16x8_t*)&A_lds[((ks_w * 4 + mt_w) * 64 + lane0 + 16) * 8]   = o1;
    }
    __syncthreads();

    // ---- MFMA ----
    const int kgb = kc * (SEND_PER_KC / 2) + it * 4;  // global kstep base
    if (nt == 0) {
      #pragma unroll
      for (int ks = 0; ks < 4; ++ks) {
        const bf16x8_t b =
            *(const bf16x8_t*)&Bs[((size_t)((kgb + ks) * NT_S + w) * 64 + lane) * 8];
        #pragma unroll
        for (int mt = 0; mt < 4; ++mt) {
          const bf16x8_t a =
              *(const bf16x8_t*)&A_lds[((ks * 4 + mt) * 64 + lane) * 8];
          acc[mt] = __builtin_amdgcn_mfma_f32_16x16x32_bf16(a, b, acc[mt], 0, 0, 0);
        }
      }
    } else {
      #pragma unroll
      for (int ks = 0; ks < 4; ++ks) {
        const bf16x8_t b0 =
            *(const bf16x8_t*)&Bv[((size_t)((kgb + ks) * NT_V + 2 * w) * 64 + lane) * 8];
        const bf16x8_t b1 =
            *(const bf16x8_t*)&Bv[((size_t)((kgb + ks) * NT_V + 2 * w + 1) * 64 + lane) * 8];
        #pragma unroll
        for (int mt = 0; mt < 4; ++mt) {
          const bf16x8_t a =
              *(const bf16x8_t*)&A_lds[((ks * 4 + mt) * 64 + lane) * 8];
          acc[mt * 2 + 0] = __builtin_amdgcn_mfma_f32_16x16x32_bf16(a, b0, acc[mt * 2 + 0], 0, 0, 0);
          acc[mt * 2 + 1] = __builtin_amdgcn_mfma_f32_16x16x32_bf16(a, b1, acc[mt * 2 + 1], 0, 0, 0);
        }
      }
    }
    __syncthreads();
  }

  // ---- epilogue: write partials (each element written exactly once) ----
  const int rowq = (lane >> 4) << 2;     // D row = (lane>>4)*4 + reg
  if (nt == 0) {
    const int col = w * 16 + (lane & 15);
    #pragma unroll
    for (int mt = 0; mt < 4; ++mt) {
      #pragma unroll
      for (int reg = 0; reg < 4; ++reg) {
        const int row = mb * 64 + mt * 16 + rowq + reg;
        Ps[((size_t)kc * NN + row) * FF + col] = acc[mt][reg];
      }
    }
  } else {
    #pragma unroll
    for (int j = 0; j < 2; ++j) {
      const int col = (2 * w + j) * 16 + (lane & 15);
      #pragma unroll
      for (int mt = 0; mt < 4; ++mt) {
        #pragma unroll
        for (int reg = 0; reg < 4; ++reg) {
          const int row = mb * 64 + mt * 16 + rowq + reg;
          Pv[((size_t)kc * NN + row) * 256 + col] = acc[mt * 2 + j][reg];
        }
      }
    }
  }
}

// ---------------------------------------------------------------------------
// node update: reduce splitK partials, combine C1 - x*C2 into agg_v, then
// hs = silu(hs + agg_s@Wss + inv@Wvs); hv += agg_v@Wvv; hsv = hs_new@Wsv_next
// ---------------------------------------------------------------------------
__global__ __launch_bounds__(256) void node_kernel(
    const float* __restrict__ Ps,       // [SPLITK][768][128]
    const float* __restrict__ Pv,       // [SPLITK][768][256]
    const float* __restrict__ x,
    const float* __restrict__ Wss,
    const float* __restrict__ Wvs,
    const float* __restrict__ Wvv,
    const float* __restrict__ Wsv_next,
    float* __restrict__ hs,
    float* __restrict__ hsv,
    float* __restrict__ hv,
    int has_next)
{
  __shared__ float as_l[FF];
  __shared__ float pvs[256];
  __shared__ float av_l[192];
  __shared__ float inv_l[VV];
  __shared__ float hsn[FF];
  const int n = blockIdx.x, t = threadIdx.x;

  if (t < FF) {
    float a = 0.f;
    #pragma unroll
    for (int kc = 0; kc < SPLITK; ++kc) a += Ps[((size_t)kc * NN + n) * FF + t];
    as_l[t] = a;
  }
  {
    float a = 0.f;
    #pragma unroll
    for (int kc = 0; kc < SPLITK; ++kc) a += Pv[((size_t)kc * NN + n) * 256 + t];
    pvs[t] = a;
  }
  __syncthreads();
  if (t < 192) {
    const int v = t / 3, dd = t - v * 3;
    av_l[t] = pvs[dd * 64 + v] - x[n * 3 + dd] * pvs[192 + v];
  }
  __syncthreads();
  if (t < VV) {
    const float a0 = av_l[t * 3 + 0], a1 = av_l[t * 3 + 1], a2 = av_l[t * 3 + 2];
    inv_l[t] = a0 * a0 + a1 * a1 + a2 * a2;
  }
  __syncthreads();
  if (t < FF) {
    float acc = hs[n * FF + t];
    #pragma unroll 4
    for (int k = 0; k < FF; ++k) acc += as_l[k] * Wss[k * FF + t];
    #pragma unroll 4
    for (int v = 0; v < VV; ++v) acc += inv_l[v] * Wvs[v * FF + t];
    const float hnew = silu_f(acc);
    hs[n * FF + t] = hnew;
    hsn[t] = hnew;
  }
  if (t < 192) {
    const int w = t / 3, d = t - w * 3;
    float acc = hv[n * 192 + t];
    #pragma unroll 4
    for (int v = 0; v < VV; ++v) acc += av_l[v * 3 + d] * Wvv[v * VV + w];
    hv[n * 192 + t] = acc;
  }
  __syncthreads();
  if (has_next && t < VV) {
    float acc = 0.f;
    #pragma unroll 4
    for (int f = 0; f < FF; ++f) acc += hsn[f] * Wsv_next[f * VV + t];
    hsv[n * VV + t] = acc;
  }
}

// ---------------------------------------------------------------------------
// readout
// ---------------------------------------------------------------------------
__global__ __launch_bounds__(192) void readout_kernel(
    const float* __restrict__ hs,
    const float* __restrict__ hv,
    const float* __restrict__ Wro_s1,
    const float* __restrict__ Wro_s2,
    const float* __restrict__ Wro_v1,
    const float* __restrict__ Wro_v2,
    float* __restrict__ out)
{
  __shared__ float hs_l[FF];
  __shared__ float hv_l[192];
  __shared__ float t1[FF];
  __shared__ float tv1[192];
  const int n = blockIdx.x, t = threadIdx.x;
  if (t < FF) hs_l[t] = hs[n * FF + t];
  hv_l[t] = hv[n * 192 + t];
  __syncthreads();
  if (t < FF) {
    float acc = 0.f;
    #pragma unroll 4
    for (int k = 0; k < FF; ++k) acc += hs_l[k] * Wro_s1[k * FF + t];
    t1[t] = silu_f(acc);
  }
  {
    const int w = t / 3, d = t - w * 3;
    float acc = 0.f;
    #pragma unroll 4
    for (int v = 0; v < VV; ++v) acc += hv_l[v * 3 + d] * Wro_v1[v * VV + w];
    tv1[t] = acc;
  }
  __syncthreads();
  if (t < 64) {
    float acc = 0.f;
    #pragma unroll 4
    for (int f = 0; f < FF; ++f) acc += t1[f] * Wro_s2[f * 64 + t];
    out[n * 160 + t] = acc;
  }
  if (t >= 64 && t < 160) {
    const int j = t - 64;
    const int w2 = j / 3, d = j - w2 * 3;
    float acc = 0.f;
    #pragma unroll 4
    for (int w = 0; w < VV; ++w) acc += tv1[w * 3 + d] * Wro_v2[w * 32 + w2];
    out[n * 160 + 64 + j] = acc;
  }
}

// ---------------------------------------------------------------------------
extern "C" void kernel_launch(void* const* d_in, const int* in_sizes, int n_in,
                              void* d_out, int out_size, void* d_ws, size_t ws_size,
                              hipStream_t stream) {
  const float* x      = (const float*)d_in[0];
  const float* embed  = (const float*)d_in[3];
  const float* Wr1    = (const float*)d_in[4];   // [2][1][16]
  const float* Wr2s   = (const float*)d_in[5];   // [2][16][128]
  const float* Wr2v   = (const float*)d_in[6];   // [2][16][64]
  const float* Wsv    = (const float*)d_in[7];   // [2][128][64]
  const float* Wss    = (const float*)d_in[8];   // [2][128][128]
  const float* Wvs    = (const float*)d_in[9];   // [2][64][128]
  const float* Wvv    = (const float*)d_in[10];  // [2][64][64]
  const float* Wro_s1 = (const float*)d_in[11];
  const float* Wro_s2 = (const float*)d_in[12];
  const float* Wro_v1 = (const float*)d_in[13];
  const float* Wro_v2 = (const float*)d_in[14];

  float* ws_f = (float*)d_ws;
  float* hs  = ws_f;                       // 768*128
  float* hsv = hs + NN * FF;               // 768*64
  float* hv  = hsv + NN * VV;              // 768*192
  float* Ps  = hv + NN * 192;              // 12*768*128
  float* Pv  = Ps + (size_t)SPLITK * NN * FF;   // 12*768*256
  unsigned short* Bs = (unsigned short*)(Pv + (size_t)SPLITK * NN * 256);
  unsigned short* Bv = Bs + (size_t)12288 * 128;
  float* out = (float*)d_out;

  init_kernel<<<NN, 192, 0, stream>>>(embed, Wsv, hs, hsv, hv);

  for (int l = 0; l < 2; ++l) {
    prep_kernel<<<2304, 256, 0, stream>>>(
        hs, hsv, x, Wr2s + l * RH * FF, Wr2v + l * RH * VV, Bs, Bv);
    edge_gemm<<<12 * 2 * SPLITK, 512, 0, stream>>>(
        x, Bs, Bv, Wr1 + l * RH, Ps, Pv);
    node_kernel<<<NN, 256, 0, stream>>>(
        Ps, Pv, x, Wss + l * FF * FF, Wvs + l * VV * FF, Wvv + l * VV * VV,
        Wsv + ((l + 1) < 2 ? (l + 1) * FF * VV : 0), hs, hsv, hv,
        (l + 1) < 2 ? 1 : 0);
  }

  readout_kernel<<<NN, 192, 0, stream>>>(hs, hv, Wro_s1, Wro_s2, Wro_v1,
                                         Wro_v2, out);
}

// Round 4
// 133.346 us; speedup vs baseline: 1.2279x; 1.2279x over previous
//
#include <hip/hip_runtime.h>
#include <math.h>

#define NN 768
#define FF 128
#define VV 64
#define RH 16
#define SPLITK 24
#define SEND_PER_KC 32          // 768 / SPLITK
#define NITER 4                 // SEND_PER_KC / 8 senders per iter
#define KSTEPS 384              // 12288 / 32
#define NT_S 8                  // scalar n-tiles (128/16)
#define NT_V 16                 // vector n-tiles (256/16)
#define MB_N 6                  // M-blocks (768/128)

typedef __attribute__((ext_vector_type(8))) short bf16x8_t;
typedef __attribute__((ext_vector_type(4))) float f32x4;

__device__ __forceinline__ float silu_f(float a) {
  return a / (1.0f + __expf(-a));
}

__device__ __forceinline__ unsigned short f2bf(float f) {
  unsigned u = __builtin_bit_cast(unsigned, f);
  unsigned r = (u + 0x7FFFu + ((u >> 16) & 1u)) >> 16;
  return (unsigned short)r;
}

// ---------------------------------------------------------------------------
// init: hs[n] = embed row; hsv[n] = embed @ Wsv[0]; hv = 0
// ---------------------------------------------------------------------------
__global__ __launch_bounds__(192) void init_kernel(
    const float* __restrict__ embed, const float* __restrict__ Wsv0,
    float* __restrict__ hs, float* __restrict__ hsv, float* __restrict__ hv)
{
  const int n = blockIdx.x, t = threadIdx.x;
  hv[n * 192 + t] = 0.0f;
  if (t < FF) hs[n * FF + t] = embed[t];
  if (t < VV) {
    float acc = 0.f;
    #pragma unroll 8
    for (int f = 0; f < FF; ++f) acc += embed[f] * Wsv0[f * VV + t];
    hsv[n * VV + t] = acc;
  }
}

// ---------------------------------------------------------------------------
// prep: build B matrices in MFMA-fragment-major layout (bf16).
// K index k = s*16 + h; 16x16x32 B-fragment: lane holds 8 contiguous k.
//   Bs[k][f]        = hs[s][f]  * Wr2s[h][f] / 64                 (N=128)
//   Bv[k][d*64+v]   = x[s][d]   * hsv[s][v] * Wr2v[h][v] / 64     (N=192)
//   Bv[k][192+v]    =             hsv[s][v] * Wr2v[h][v] / 64     (N=64)
// ---------------------------------------------------------------------------
__global__ __launch_bounds__(256) void prep_kernel(
    const float* __restrict__ hs, const float* __restrict__ hsv,
    const float* __restrict__ x,
    const float* __restrict__ Wr2s,   // [16][128] layer slice
    const float* __restrict__ Wr2v,   // [16][64]  layer slice
    unsigned short* __restrict__ Bs, unsigned short* __restrict__ Bv)
{
  const int gid   = blockIdx.x * 256 + threadIdx.x;
  const int lane  = gid & 63;
  const int tmp   = gid >> 6;
  const int ntile = tmp % 24;
  const int kstep = tmp / 24;
  if (kstep >= KSTEPS) return;
  const int qq = lane >> 4;              // octet index 0..3
  const int s  = kstep * 2 + (qq >> 1);
  const int hb = (qq & 1) * 8;

  bf16x8_t o;
  if (ntile < NT_S) {
    const int f = ntile * 16 + (lane & 15);
    const float hf = hs[s * FF + f] * 0.015625f;
    #pragma unroll
    for (int e = 0; e < 8; ++e)
      o[e] = (short)f2bf(hf * Wr2s[(hb + e) * FF + f]);
    *(bf16x8_t*)&Bs[((size_t)(kstep * NT_S + ntile) * 64 + lane) * 8] = o;
  } else {
    const int nt2 = ntile - NT_S;
    const int n   = nt2 * 16 + (lane & 15);
    int v; float scale;
    if (n < 192) { const int dd = n >> 6; v = n & 63;
                   scale = x[s * 3 + dd] * hsv[s * VV + v] * 0.015625f; }
    else         { v = n - 192; scale = hsv[s * VV + v] * 0.015625f; }
    #pragma unroll
    for (int e = 0; e < 8; ++e)
      o[e] = (short)f2bf(scale * Wr2v[(hb + e) * VV + v]);
    *(bf16x8_t*)&Bv[((size_t)(kstep * NT_V + nt2) * 64 + lane) * 8] = o;
  }
}

// ---------------------------------------------------------------------------
// edge GEMM: M=128 rows/block. grid = 6 Mb x {scalar,vector} x SPLITK=24,
// XCD-swizzled so the 6 M-blocks sharing a B slice land on one XCD.
// Per iter (8 senders = 4 ksteps): 1024 (r,s) pairs -> 2 per thread; A
// fragments written to LDS; then 8 waves MFMA (scalar: 1 ntile x 8 mtiles,
// vector: 2 ntiles x 8 mtiles). Partials per K-chunk, no atomics.
// ---------------------------------------------------------------------------
__global__ __launch_bounds__(512) void edge_gemm(
    const float* __restrict__ x,
    const unsigned short* __restrict__ Bs,
    const unsigned short* __restrict__ Bv,
    const float* __restrict__ Wr1,    // [16] layer slice
    float* __restrict__ Ps,           // [SPLITK][768][128]
    float* __restrict__ Pv)           // [SPLITK][768][256]
{
  __shared__ unsigned short A_lds[4 * 8 * 64 * 8];  // 32 KB: [ks][mt][lane][8]

  // de-swizzle blockIdx: b = (g&7) + 8*((g>>3)*6 + mb), g = nt*24 + kc
  const int b   = blockIdx.x;
  const int low = b & 7;
  const int m   = b >> 3;            // 0..35
  const int gh  = m / 6;             // 0..5
  const int mb  = m - gh * 6;        // 0..5
  const int g   = gh * 8 + low;      // 0..47
  const int nt  = g / 24;
  const int kc  = g - nt * 24;

  const int tid  = threadIdx.x;
  const int lane = tid & 63;
  const int w    = tid >> 6;

  float wr1[RH];
  #pragma unroll
  for (int h = 0; h < RH; ++h) wr1[h] = Wr1[h];

  // A-gen: this thread owns pairs p = tid and p + 512
  const int r_local = tid & 127;
  const int s_ii0   = tid >> 7;        // 0..3
  const int r = mb * 128 + r_local;
  const float xr0 = x[r * 3 + 0], xr1 = x[r * 3 + 1], xr2 = x[r * 3 + 2];
  const int mt_w  = r_local >> 4;
  const int lmod  = r_local & 15;

  f32x4 acc[16];
  const int nacc = nt ? 16 : 8;
  #pragma unroll
  for (int i = 0; i < 16; ++i) acc[i] = (f32x4){0.f, 0.f, 0.f, 0.f};

  for (int it = 0; it < NITER; ++it) {
    // ---- A generation ----
    #pragma unroll
    for (int pp = 0; pp < 2; ++pp) {
      const int s_ii = s_ii0 + pp * 4;
      const int ks_w = s_ii >> 1;
      const int lane0 = lmod + ((s_ii & 1) << 5);
      const int s = kc * SEND_PER_KC + it * 8 + s_ii;
      const float vx = x[s * 3 + 0] - xr0;
      const float vy = x[s * 3 + 1] - xr1;
      const float vz = x[s * 3 + 2] - xr2;
      const float dd = sqrtf(vx * vx + vy * vy + vz * vz);
      const float iv = 1.0f / (dd + 1e-8f);
      const float mulf = nt ? iv : 1.0f;
      bf16x8_t o0, o1;
      #pragma unroll
      for (int h = 0; h < 8; ++h)
        o0[h] = (short)f2bf(silu_f(dd * wr1[h]) * mulf);
      #pragma unroll
      for (int h = 8; h < 16; ++h)
        o1[h - 8] = (short)f2bf(silu_f(dd * wr1[h]) * mulf);
      *(bf16x8_t*)&A_lds[((ks_w * 8 + mt_w) * 64 + lane0) * 8]      = o0;
      *(bf16x8_t*)&A_lds[((ks_w * 8 + mt_w) * 64 + lane0 + 16) * 8] = o1;
    }
    __syncthreads();

    // ---- MFMA ----
    const int kgb = kc * (SEND_PER_KC / 2) + it * 4;  // global kstep base
    if (nt == 0) {
      #pragma unroll
      for (int ks = 0; ks < 4; ++ks) {
        const bf16x8_t bfr =
            *(const bf16x8_t*)&Bs[((size_t)((kgb + ks) * NT_S + w) * 64 + lane) * 8];
        #pragma unroll
        for (int mt = 0; mt < 8; ++mt) {
          const bf16x8_t a =
              *(const bf16x8_t*)&A_lds[((ks * 8 + mt) * 64 + lane) * 8];
          acc[mt] = __builtin_amdgcn_mfma_f32_16x16x32_bf16(a, bfr, acc[mt], 0, 0, 0);
        }
      }
    } else {
      #pragma unroll
      for (int ks = 0; ks < 4; ++ks) {
        const bf16x8_t b0 =
            *(const bf16x8_t*)&Bv[((size_t)((kgb + ks) * NT_V + 2 * w) * 64 + lane) * 8];
        const bf16x8_t b1 =
            *(const bf16x8_t*)&Bv[((size_t)((kgb + ks) * NT_V + 2 * w + 1) * 64 + lane) * 8];
        #pragma unroll
        for (int mt = 0; mt < 8; ++mt) {
          const bf16x8_t a =
              *(const bf16x8_t*)&A_lds[((ks * 8 + mt) * 64 + lane) * 8];
          acc[mt * 2 + 0] = __builtin_amdgcn_mfma_f32_16x16x32_bf16(a, b0, acc[mt * 2 + 0], 0, 0, 0);
          acc[mt * 2 + 1] = __builtin_amdgcn_mfma_f32_16x16x32_bf16(a, b1, acc[mt * 2 + 1], 0, 0, 0);
        }
      }
    }
    __syncthreads();
  }
  (void)nacc;

  // ---- epilogue: write partials (each element written exactly once) ----
  const int rowq = (lane >> 4) << 2;     // D row = (lane>>4)*4 + reg
  if (nt == 0) {
    const int col = w * 16 + (lane & 15);
    #pragma unroll
    for (int mt = 0; mt < 8; ++mt) {
      #pragma unroll
      for (int reg = 0; reg < 4; ++reg) {
        const int row = mb * 128 + mt * 16 + rowq + reg;
        Ps[((size_t)kc * NN + row) * FF + col] = acc[mt][reg];
      }
    }
  } else {
    #pragma unroll
    for (int j = 0; j < 2; ++j) {
      const int col = (2 * w + j) * 16 + (lane & 15);
      #pragma unroll
      for (int mt = 0; mt < 8; ++mt) {
        #pragma unroll
        for (int reg = 0; reg < 4; ++reg) {
          const int row = mb * 128 + mt * 16 + rowq + reg;
          Pv[((size_t)kc * NN + row) * 256 + col] = acc[mt * 2 + j][reg];
        }
      }
    }
  }
}

// ---------------------------------------------------------------------------
// reduce splitK partials, fully coalesced float4 loads, 24-deep ILP.
// grid covers (768*128 + 768*256)/4 float4 elements exactly.
// ---------------------------------------------------------------------------
#define ES4 (NN * FF / 4)     // 24576
#define EV4 (NN * 256 / 4)    // 49152
__global__ __launch_bounds__(256) void reduce_kernel(
    const float* __restrict__ Ps, const float* __restrict__ Pv,
    float* __restrict__ aggs, float* __restrict__ pvsum)
{
  const int gid = blockIdx.x * 256 + threadIdx.x;
  if (gid < ES4) {
    const f32x4* p = (const f32x4*)Ps + gid;
    f32x4 a = (f32x4){0.f, 0.f, 0.f, 0.f};
    #pragma unroll
    for (int kc = 0; kc < SPLITK; ++kc) {
      const f32x4 v = p[(size_t)kc * ES4];
      a.x += v.x; a.y += v.y; a.z += v.z; a.w += v.w;
    }
    ((f32x4*)aggs)[gid] = a;
  } else {
    const int g2 = gid - ES4;
    const f32x4* p = (const f32x4*)Pv + g2;
    f32x4 a = (f32x4){0.f, 0.f, 0.f, 0.f};
    #pragma unroll
    for (int kc = 0; kc < SPLITK; ++kc) {
      const f32x4 v = p[(size_t)kc * EV4];
      a.x += v.x; a.y += v.y; a.z += v.z; a.w += v.w;
    }
    ((f32x4*)pvsum)[g2] = a;
  }
}

// ---------------------------------------------------------------------------
// node update (512 threads, 4-way K-split GEMVs):
//   av = C1 - x*C2; inv = |av|^2;
//   hs = silu(hs + aggs@Wss + inv@Wvs); hv += av@Wvv; hsv = hs_new@Wsv_next
// ---------------------------------------------------------------------------
__global__ __launch_bounds__(512) void node_kernel(
    const float* __restrict__ aggs,     // [768][128]
    const float* __restrict__ pvsum,    // [768][256]
    const float* __restrict__ x,
    const float* __restrict__ Wss,
    const float* __restrict__ Wvs,
    const float* __restrict__ Wvv,
    const float* __restrict__ Wsv_next,
    float* __restrict__ hs,
    float* __restrict__ hsv,
    float* __restrict__ hv,
    int has_next)
{
  __shared__ float as_l[FF];
  __shared__ float pvs_l[256];
  __shared__ float av_l[192];
  __shared__ float inv_l[VV];
  __shared__ float hsn[FF];
  __shared__ float red[512];
  __shared__ float red2[384];
  const int n = blockIdx.x, t = threadIdx.x;

  if (t < FF) as_l[t] = aggs[n * FF + t];
  if (t >= 128 && t < 384) pvs_l[t - 128] = pvsum[n * 256 + (t - 128)];
  __syncthreads();

  if (t < VV) {
    const float base = pvs_l[192 + t];
    const float a0 = pvs_l[t]       - x[n * 3 + 0] * base;
    const float a1 = pvs_l[64 + t]  - x[n * 3 + 1] * base;
    const float a2 = pvs_l[128 + t] - x[n * 3 + 2] * base;
    av_l[t * 3 + 0] = a0; av_l[t * 3 + 1] = a1; av_l[t * 3 + 2] = a2;
    inv_l[t] = a0 * a0 + a1 * a1 + a2 * a2;
  }
  __syncthreads();

  // hs partials: 4-way split over K
  {
    const int f = t & 127, part = t >> 7;
    float acc = 0.f;
    const float* wp = Wss + (part * 32) * FF + f;
    #pragma unroll 8
    for (int kk = 0; kk < 32; ++kk) acc += as_l[part * 32 + kk] * wp[kk * FF];
    const float* vp = Wvs + (part * 16) * FF + f;
    #pragma unroll 8
    for (int vv = 0; vv < 16; ++vv) acc += inv_l[part * 16 + vv] * vp[vv * FF];
    red[part * 128 + f] = acc;
  }
  __syncthreads();

  // hs finalize || hv partials (2-way split over v)
  if (t < FF) {
    const float hnew =
        silu_f(hs[n * FF + t] + red[t] + red[128 + t] + red[256 + t] + red[384 + t]);
    hs[n * FF + t] = hnew;
    hsn[t] = hnew;
  }
  if (t < 384) {
    const int part = t / 192, j = t - part * 192;
    const int wv = j / 3, d = j - wv * 3;
    float acc = 0.f;
    const float* vp = Wvv + (part * 32) * VV + wv;
    #pragma unroll 8
    for (int v = 0; v < 32; ++v) acc += av_l[(part * 32 + v) * 3 + d] * vp[v * VV];
    red2[part * 192 + j] = acc;
  }
  __syncthreads();

  // hv finalize || hsv partials (4-way split over f)
  if (t < 192) hv[n * 192 + t] += red2[t] + red2[192 + t];
  if (has_next) {
    if (t < 256) {
      const int v = t & 63, part = t >> 6;
      float acc = 0.f;
      const float* wp = Wsv_next + (part * 32) * VV + v;
      #pragma unroll 8
      for (int f = 0; f < 32; ++f) acc += hsn[part * 32 + f] * wp[f * VV];
      red[t] = acc;
    }
    __syncthreads();
    if (t < VV) hsv[n * VV + t] = red[t] + red[64 + t] + red[128 + t] + red[192 + t];
  }
}

// ---------------------------------------------------------------------------
// readout (512 threads, K-split GEMVs)
// ---------------------------------------------------------------------------
__global__ __launch_bounds__(512) void readout_kernel(
    const float* __restrict__ hs,
    const float* __restrict__ hv,
    const float* __restrict__ Wro_s1,
    const float* __restrict__ Wro_s2,
    const float* __restrict__ Wro_v1,
    const float* __restrict__ Wro_v2,
    float* __restrict__ out)
{
  __shared__ float hs_l[FF];
  __shared__ float hv_l[192];
  __shared__ float t1[FF];
  __shared__ float tv1[192];
  __shared__ float redA[512];
  __shared__ float redB[384];
  const int n = blockIdx.x, t = threadIdx.x;
  if (t < FF) hs_l[t] = hs[n * FF + t];
  if (t >= 128 && t < 320) hv_l[t - 128] = hv[n * 192 + (t - 128)];
  __syncthreads();

  // t1 partials
  {
    const int f = t & 127, part = t >> 7;
    float acc = 0.f;
    const float* wp = Wro_s1 + (part * 32) * FF + f;
    #pragma unroll 8
    for (int kk = 0; kk < 32; ++kk) acc += hs_l[part * 32 + kk] * wp[kk * FF];
    redA[part * 128 + f] = acc;
  }
  __syncthreads();
  if (t < FF) t1[t] = silu_f(redA[t] + redA[128 + t] + redA[256 + t] + redA[384 + t]);
  if (t < 384) {  // tv1 partials (2-way over v)
    const int part = t / 192, j = t - part * 192;
    const int wv = j / 3, d = j - wv * 3;
    float acc = 0.f;
    const float* vp = Wro_v1 + (part * 32) * VV + wv;
    #pragma unroll 8
    for (int v = 0; v < 32; ++v) acc += hv_l[(part * 32 + v) * 3 + d] * vp[v * VV];
    redB[part * 192 + j] = acc;
  }
  __syncthreads();
  if (t < 192) tv1[t] = redB[t] + redB[192 + t];
  if (t < 256) {  // out_s partials (4-way over f)
    const int o = t & 63, part = t >> 6;
    float acc = 0.f;
    const float* wp = Wro_s2 + (part * 32) * 64 + o;
    #pragma unroll 8
    for (int f = 0; f < 32; ++f) acc += t1[part * 32 + f] * wp[f * 64];
    redA[t] = acc;
  }
  __syncthreads();
  if (t < 64) out[n * 160 + t] = redA[t] + redA[64 + t] + redA[128 + t] + redA[192 + t];
  if (t < 192) {  // out_v partials (2-way over w)
    const int part = t / 96, j = t - part * 96;
    const int w2 = j / 3, d = j - w2 * 3;
    float acc = 0.f;
    const float* vp = Wro_v2 + (part * 32) * 32 + w2;
    #pragma unroll 8
    for (int wv = 0; wv < 32; ++wv) acc += tv1[(part * 32 + wv) * 3 + d] * vp[wv * 32];
    redB[part * 96 + j] = acc;
  }
  __syncthreads();
  if (t < 96) out[n * 160 + 64 + t] = redB[t] + redB[96 + t];
}

// ---------------------------------------------------------------------------
extern "C" void kernel_launch(void* const* d_in, const int* in_sizes, int n_in,
                              void* d_out, int out_size, void* d_ws, size_t ws_size,
                              hipStream_t stream) {
  const float* x      = (const float*)d_in[0];
  const float* embed  = (const float*)d_in[3];
  const float* Wr1    = (const float*)d_in[4];   // [2][1][16]
  const float* Wr2s   = (const float*)d_in[5];   // [2][16][128]
  const float* Wr2v   = (const float*)d_in[6];   // [2][16][64]
  const float* Wsv    = (const float*)d_in[7];   // [2][128][64]
  const float* Wss    = (const float*)d_in[8];   // [2][128][128]
  const float* Wvs    = (const float*)d_in[9];   // [2][64][128]
  const float* Wvv    = (const float*)d_in[10];  // [2][64][64]
  const float* Wro_s1 = (const float*)d_in[11];
  const float* Wro_s2 = (const float*)d_in[12];
  const float* Wro_v1 = (const float*)d_in[13];
  const float* Wro_v2 = (const float*)d_in[14];

  float* ws_f = (float*)d_ws;
  float* hs    = ws_f;                      // 768*128
  float* hsv   = hs + NN * FF;              // 768*64
  float* hv    = hsv + NN * VV;             // 768*192
  float* aggs  = hv + NN * 192;             // 768*128
  float* pvsum = aggs + NN * FF;            // 768*256
  float* Ps    = pvsum + NN * 256;          // 24*768*128
  float* Pv    = Ps + (size_t)SPLITK * NN * FF;   // 24*768*256
  unsigned short* Bs = (unsigned short*)(Pv + (size_t)SPLITK * NN * 256);
  unsigned short* Bv = Bs + (size_t)12288 * 128;
  float* out = (float*)d_out;

  init_kernel<<<NN, 192, 0, stream>>>(embed, Wsv, hs, hsv, hv);

  for (int l = 0; l < 2; ++l) {
    prep_kernel<<<2304, 256, 0, stream>>>(
        hs, hsv, x, Wr2s + l * RH * FF, Wr2v + l * RH * VV, Bs, Bv);
    edge_gemm<<<MB_N * 2 * SPLITK, 512, 0, stream>>>(
        x, Bs, Bv, Wr1 + l * RH, Ps, Pv);
    reduce_kernel<<<(ES4 + EV4) / 256, 256, 0, stream>>>(Ps, Pv, aggs, pvsum);
    node_kernel<<<NN, 512, 0, stream>>>(
        aggs, pvsum, x, Wss + l * FF * FF, Wvs + l * VV * FF, Wvv + l * VV * VV,
        Wsv + ((l + 1) < 2 ? (l + 1) * FF * VV : 0), hs, hsv, hv,
        (l + 1) < 2 ? 1 : 0);
  }

  readout_kernel<<<NN, 512, 0, stream>>>(hs, hv, Wro_s1, Wro_s2, Wro_v1,
                                         Wro_v2, out);
}

// Round 5
// 109.187 us; speedup vs baseline: 1.4996x; 1.2213x over previous
//
#include <hip/hip_runtime.h>
#include <math.h>

#define NN 768
#define FF 128
#define VV 64
#define RH 16
#define SPLITK 24
#define SEND_PER_KC 32          // 768 / SPLITK
#define NITER 4                 // SEND_PER_KC / 8 senders per iter
#define KSTEPS 384              // 12288 / 32
#define NT_S 8                  // scalar n-tiles (128/16)
#define NT_V 16                 // vector n-tiles (256/16)
#define MB_N 24                 // M-blocks (768/32)

typedef __attribute__((ext_vector_type(8))) short bf16x8_t;
typedef __attribute__((ext_vector_type(4))) float f32x4;

__device__ __forceinline__ float silu_f(float a) {
  return a / (1.0f + __expf(-a));
}

__device__ __forceinline__ unsigned short f2bf(float f) {
  unsigned u = __builtin_bit_cast(unsigned, f);
  unsigned r = (u + 0x7FFFu + ((u >> 16) & 1u)) >> 16;
  return (unsigned short)r;
}

// ---------------------------------------------------------------------------
// init: hs[n] = embed row; hsv[n] = embed @ Wsv[0]; hv = 0
// ---------------------------------------------------------------------------
__global__ __launch_bounds__(192) void init_kernel(
    const float* __restrict__ embed, const float* __restrict__ Wsv0,
    float* __restrict__ hs, float* __restrict__ hsv, float* __restrict__ hv)
{
  const int n = blockIdx.x, t = threadIdx.x;
  hv[n * 192 + t] = 0.0f;
  if (t < FF) hs[n * FF + t] = embed[t];
  if (t < VV) {
    float acc = 0.f;
    #pragma unroll 8
    for (int f = 0; f < FF; ++f) acc += embed[f] * Wsv0[f * VV + t];
    hsv[n * VV + t] = acc;
  }
}

// ---------------------------------------------------------------------------
// prep: build B matrices in MFMA-fragment-major layout (bf16).
// K index k = s*16 + h; 16x16x32 B-fragment: lane holds 8 contiguous k.
//   Bs[k][f]        = hs[s][f]  * Wr2s[h][f] / 64                 (N=128)
//   Bv[k][d*64+v]   = x[s][d]   * hsv[s][v] * Wr2v[h][v] / 64     (N=192)
//   Bv[k][192+v]    =             hsv[s][v] * Wr2v[h][v] / 64     (N=64)
// ---------------------------------------------------------------------------
__global__ __launch_bounds__(256) void prep_kernel(
    const float* __restrict__ hs, const float* __restrict__ hsv,
    const float* __restrict__ x,
    const float* __restrict__ Wr2s,   // [16][128] layer slice
    const float* __restrict__ Wr2v,   // [16][64]  layer slice
    unsigned short* __restrict__ Bs, unsigned short* __restrict__ Bv)
{
  const int gid   = blockIdx.x * 256 + threadIdx.x;
  const int lane  = gid & 63;
  const int tmp   = gid >> 6;
  const int ntile = tmp % 24;
  const int kstep = tmp / 24;
  if (kstep >= KSTEPS) return;
  const int qq = lane >> 4;              // octet index 0..3
  const int s  = kstep * 2 + (qq >> 1);
  const int hb = (qq & 1) * 8;

  bf16x8_t o;
  if (ntile < NT_S) {
    const int f = ntile * 16 + (lane & 15);
    const float hf = hs[s * FF + f] * 0.015625f;
    #pragma unroll
    for (int e = 0; e < 8; ++e)
      o[e] = (short)f2bf(hf * Wr2s[(hb + e) * FF + f]);
    *(bf16x8_t*)&Bs[((size_t)(kstep * NT_S + ntile) * 64 + lane) * 8] = o;
  } else {
    const int nt2 = ntile - NT_S;
    const int n   = nt2 * 16 + (lane & 15);
    int v; float scale;
    if (n < 192) { const int dd = n >> 6; v = n & 63;
                   scale = x[s * 3 + dd] * hsv[s * VV + v] * 0.015625f; }
    else         { v = n - 192; scale = hsv[s * VV + v] * 0.015625f; }
    #pragma unroll
    for (int e = 0; e < 8; ++e)
      o[e] = (short)f2bf(scale * Wr2v[(hb + e) * VV + v]);
    *(bf16x8_t*)&Bv[((size_t)(kstep * NT_V + nt2) * 64 + lane) * 8] = o;
  }
}

// ---------------------------------------------------------------------------
// edge GEMM v2: M=32 rows/block, 256 threads (4 waves).
// grid = 24 Mb x {scalar,vector} x SPLITK=24 = 1152 blocks (18 waves/CU),
// XCD-swizzled so the 24 M-blocks sharing one B slice land on one XCD.
// All x coords preloaded to registers; K-loop is pure VALU->LDS->MFMA.
// scalar wave: ntiles 2w,2w+1 x 2 mtiles; vector wave: ntiles 4w..4w+3 x 2.
// Partials per K-chunk, no atomics.
// ---------------------------------------------------------------------------
__global__ __launch_bounds__(256) void edge_gemm(
    const float* __restrict__ x,
    const unsigned short* __restrict__ Bs,
    const unsigned short* __restrict__ Bv,
    const float* __restrict__ Wr1,    // [16] layer slice
    float* __restrict__ Ps,           // [SPLITK][768][128]
    float* __restrict__ Pv)           // [SPLITK][768][256]
{
  __shared__ unsigned short A_lds[4 * 2 * 64 * 8];  // 8 KB: [ks][mt][lane][8]

  // bijective XCD swizzle: 1152 = 8 * 144; XCD k gets 6 full (nt,kc) groups
  const int wg  = ((blockIdx.x & 7) * 144) + (blockIdx.x >> 3);
  const int nt  = wg / 576;
  const int rem = wg - nt * 576;
  const int kc  = rem / MB_N;
  const int mb  = rem - kc * MB_N;

  const int tid  = threadIdx.x;
  const int lane = tid & 63;
  const int w    = tid >> 6;

  float wr1[RH];
  #pragma unroll
  for (int h = 0; h < RH; ++h) wr1[h] = Wr1[h];

  // A-gen assignment: one (r,s) pair per thread per iter
  const int r_local = tid & 31;
  const int s_ii    = tid >> 5;        // 0..7
  const int r = mb * 32 + r_local;
  const int mt_w  = r_local >> 4;
  const int ks_w  = s_ii >> 1;
  const int lane0 = (r_local & 15) + ((s_ii & 1) << 5);

  const float xr0 = x[r * 3 + 0], xr1 = x[r * 3 + 1], xr2 = x[r * 3 + 2];
  float sx[NITER], sy[NITER], sz[NITER];
  #pragma unroll
  for (int it = 0; it < NITER; ++it) {
    const int s = kc * SEND_PER_KC + it * 8 + s_ii;
    sx[it] = x[s * 3 + 0]; sy[it] = x[s * 3 + 1]; sz[it] = x[s * 3 + 2];
  }

  f32x4 acc[8];
  #pragma unroll
  for (int i = 0; i < 8; ++i) acc[i] = (f32x4){0.f, 0.f, 0.f, 0.f};

  for (int it = 0; it < NITER; ++it) {
    // ---- A generation (registers only -> LDS) ----
    {
      const float vx = sx[it] - xr0;
      const float vy = sy[it] - xr1;
      const float vz = sz[it] - xr2;
      const float dd = sqrtf(vx * vx + vy * vy + vz * vz);
      const float iv = 1.0f / (dd + 1e-8f);
      const float mulf = nt ? iv : 1.0f;
      bf16x8_t o0, o1;
      #pragma unroll
      for (int h = 0; h < 8; ++h)
        o0[h] = (short)f2bf(silu_f(dd * wr1[h]) * mulf);
      #pragma unroll
      for (int h = 8; h < 16; ++h)
        o1[h - 8] = (short)f2bf(silu_f(dd * wr1[h]) * mulf);
      *(bf16x8_t*)&A_lds[((ks_w * 2 + mt_w) * 64 + lane0) * 8]      = o0;
      *(bf16x8_t*)&A_lds[((ks_w * 2 + mt_w) * 64 + lane0 + 16) * 8] = o1;
    }
    __syncthreads();

    // ---- MFMA ----
    const int kgb = kc * (SEND_PER_KC / 2) + it * 4;  // global kstep base
    if (nt == 0) {
      #pragma unroll
      for (int ks = 0; ks < 4; ++ks) {
        const bf16x8_t b0 =
            *(const bf16x8_t*)&Bs[((size_t)((kgb + ks) * NT_S + 2 * w) * 64 + lane) * 8];
        const bf16x8_t b1 =
            *(const bf16x8_t*)&Bs[((size_t)((kgb + ks) * NT_S + 2 * w + 1) * 64 + lane) * 8];
        #pragma unroll
        for (int mt = 0; mt < 2; ++mt) {
          const bf16x8_t a =
              *(const bf16x8_t*)&A_lds[((ks * 2 + mt) * 64 + lane) * 8];
          acc[mt * 2 + 0] = __builtin_amdgcn_mfma_f32_16x16x32_bf16(a, b0, acc[mt * 2 + 0], 0, 0, 0);
          acc[mt * 2 + 1] = __builtin_amdgcn_mfma_f32_16x16x32_bf16(a, b1, acc[mt * 2 + 1], 0, 0, 0);
        }
      }
    } else {
      #pragma unroll
      for (int ks = 0; ks < 4; ++ks) {
        bf16x8_t bv[4];
        #pragma unroll
        for (int j = 0; j < 4; ++j)
          bv[j] = *(const bf16x8_t*)&Bv[((size_t)((kgb + ks) * NT_V + 4 * w + j) * 64 + lane) * 8];
        #pragma unroll
        for (int mt = 0; mt < 2; ++mt) {
          const bf16x8_t a =
              *(const bf16x8_t*)&A_lds[((ks * 2 + mt) * 64 + lane) * 8];
          #pragma unroll
          for (int j = 0; j < 4; ++j)
            acc[mt * 4 + j] = __builtin_amdgcn_mfma_f32_16x16x32_bf16(a, bv[j], acc[mt * 4 + j], 0, 0, 0);
        }
      }
    }
    __syncthreads();
  }

  // ---- epilogue: write partials (each element written exactly once) ----
  const int rowq = (lane >> 4) << 2;     // D row = (lane>>4)*4 + reg
  if (nt == 0) {
    #pragma unroll
    for (int j = 0; j < 2; ++j) {
      const int col = (2 * w + j) * 16 + (lane & 15);
      #pragma unroll
      for (int mt = 0; mt < 2; ++mt) {
        #pragma unroll
        for (int reg = 0; reg < 4; ++reg) {
          const int row = mb * 32 + mt * 16 + rowq + reg;
          Ps[((size_t)kc * NN + row) * FF + col] = acc[mt * 2 + j][reg];
        }
      }
    }
  } else {
    #pragma unroll
    for (int j = 0; j < 4; ++j) {
      const int col = (4 * w + j) * 16 + (lane & 15);
      #pragma unroll
      for (int mt = 0; mt < 2; ++mt) {
        #pragma unroll
        for (int reg = 0; reg < 4; ++reg) {
          const int row = mb * 32 + mt * 16 + rowq + reg;
          Pv[((size_t)kc * NN + row) * 256 + col] = acc[mt * 4 + j][reg];
        }
      }
    }
  }
}

// ---------------------------------------------------------------------------
// reduce splitK partials, fully coalesced float4 loads, 24-deep ILP.
// ---------------------------------------------------------------------------
#define ES4 (NN * FF / 4)     // 24576
#define EV4 (NN * 256 / 4)    // 49152
__global__ __launch_bounds__(256) void reduce_kernel(
    const float* __restrict__ Ps, const float* __restrict__ Pv,
    float* __restrict__ aggs, float* __restrict__ pvsum)
{
  const int gid = blockIdx.x * 256 + threadIdx.x;
  if (gid < ES4) {
    const f32x4* p = (const f32x4*)Ps + gid;
    f32x4 a = (f32x4){0.f, 0.f, 0.f, 0.f};
    #pragma unroll
    for (int kc = 0; kc < SPLITK; ++kc) {
      const f32x4 v = p[(size_t)kc * ES4];
      a.x += v.x; a.y += v.y; a.z += v.z; a.w += v.w;
    }
    ((f32x4*)aggs)[gid] = a;
  } else {
    const int g2 = gid - ES4;
    const f32x4* p = (const f32x4*)Pv + g2;
    f32x4 a = (f32x4){0.f, 0.f, 0.f, 0.f};
    #pragma unroll
    for (int kc = 0; kc < SPLITK; ++kc) {
      const f32x4 v = p[(size_t)kc * EV4];
      a.x += v.x; a.y += v.y; a.z += v.z; a.w += v.w;
    }
    ((f32x4*)pvsum)[g2] = a;
  }
}

// ---------------------------------------------------------------------------
// node update (512 threads, 4-way K-split GEMVs):
//   av = C1 - x*C2; inv = |av|^2;
//   hs = silu(hs + aggs@Wss + inv@Wvs); hv += av@Wvv; hsv = hs_new@Wsv_next
// ---------------------------------------------------------------------------
__global__ __launch_bounds__(512) void node_kernel(
    const float* __restrict__ aggs,     // [768][128]
    const float* __restrict__ pvsum,    // [768][256]
    const float* __restrict__ x,
    const float* __restrict__ Wss,
    const float* __restrict__ Wvs,
    const float* __restrict__ Wvv,
    const float* __restrict__ Wsv_next,
    float* __restrict__ hs,
    float* __restrict__ hsv,
    float* __restrict__ hv,
    int has_next)
{
  __shared__ float as_l[FF];
  __shared__ float pvs_l[256];
  __shared__ float av_l[192];
  __shared__ float inv_l[VV];
  __shared__ float hsn[FF];
  __shared__ float red[512];
  __shared__ float red2[384];
  const int n = blockIdx.x, t = threadIdx.x;

  if (t < FF) as_l[t] = aggs[n * FF + t];
  if (t >= 128 && t < 384) pvs_l[t - 128] = pvsum[n * 256 + (t - 128)];
  __syncthreads();

  if (t < VV) {
    const float base = pvs_l[192 + t];
    const float a0 = pvs_l[t]       - x[n * 3 + 0] * base;
    const float a1 = pvs_l[64 + t]  - x[n * 3 + 1] * base;
    const float a2 = pvs_l[128 + t] - x[n * 3 + 2] * base;
    av_l[t * 3 + 0] = a0; av_l[t * 3 + 1] = a1; av_l[t * 3 + 2] = a2;
    inv_l[t] = a0 * a0 + a1 * a1 + a2 * a2;
  }
  __syncthreads();

  // hs partials: 4-way split over K
  {
    const int f = t & 127, part = t >> 7;
    float acc = 0.f;
    const float* wp = Wss + (part * 32) * FF + f;
    #pragma unroll 8
    for (int kk = 0; kk < 32; ++kk) acc += as_l[part * 32 + kk] * wp[kk * FF];
    const float* vp = Wvs + (part * 16) * FF + f;
    #pragma unroll 8
    for (int vv = 0; vv < 16; ++vv) acc += inv_l[part * 16 + vv] * vp[vv * FF];
    red[part * 128 + f] = acc;
  }
  __syncthreads();

  // hs finalize || hv partials (2-way split over v)
  if (t < FF) {
    const float hnew =
        silu_f(hs[n * FF + t] + red[t] + red[128 + t] + red[256 + t] + red[384 + t]);
    hs[n * FF + t] = hnew;
    hsn[t] = hnew;
  }
  if (t < 384) {
    const int part = t / 192, j = t - part * 192;
    const int wv = j / 3, d = j - wv * 3;
    float acc = 0.f;
    const float* vp = Wvv + (part * 32) * VV + wv;
    #pragma unroll 8
    for (int v = 0; v < 32; ++v) acc += av_l[(part * 32 + v) * 3 + d] * vp[v * VV];
    red2[part * 192 + j] = acc;
  }
  __syncthreads();

  // hv finalize || hsv partials (4-way split over f)
  if (t < 192) hv[n * 192 + t] += red2[t] + red2[192 + t];
  if (has_next) {
    if (t < 256) {
      const int v = t & 63, part = t >> 6;
      float acc = 0.f;
      const float* wp = Wsv_next + (part * 32) * VV + v;
      #pragma unroll 8
      for (int f = 0; f < 32; ++f) acc += hsn[part * 32 + f] * wp[f * VV];
      red[t] = acc;
    }
    __syncthreads();
    if (t < VV) hsv[n * VV + t] = red[t] + red[64 + t] + red[128 + t] + red[192 + t];
  }
}

// ---------------------------------------------------------------------------
// readout (512 threads, K-split GEMVs)
// ---------------------------------------------------------------------------
__global__ __launch_bounds__(512) void readout_kernel(
    const float* __restrict__ hs,
    const float* __restrict__ hv,
    const float* __restrict__ Wro_s1,
    const float* __restrict__ Wro_s2,
    const float* __restrict__ Wro_v1,
    const float* __restrict__ Wro_v2,
    float* __restrict__ out)
{
  __shared__ float hs_l[FF];
  __shared__ float hv_l[192];
  __shared__ float t1[FF];
  __shared__ float tv1[192];
  __shared__ float redA[512];
  __shared__ float redB[384];
  const int n = blockIdx.x, t = threadIdx.x;
  if (t < FF) hs_l[t] = hs[n * FF + t];
  if (t >= 128 && t < 320) hv_l[t - 128] = hv[n * 192 + (t - 128)];
  __syncthreads();

  // t1 partials
  {
    const int f = t & 127, part = t >> 7;
    float acc = 0.f;
    const float* wp = Wro_s1 + (part * 32) * FF + f;
    #pragma unroll 8
    for (int kk = 0; kk < 32; ++kk) acc += hs_l[part * 32 + kk] * wp[kk * FF];
    redA[part * 128 + f] = acc;
  }
  __syncthreads();
  if (t < FF) t1[t] = silu_f(redA[t] + redA[128 + t] + redA[256 + t] + redA[384 + t]);
  if (t < 384) {  // tv1 partials (2-way over v)
    const int part = t / 192, j = t - part * 192;
    const int wv = j / 3, d = j - wv * 3;
    float acc = 0.f;
    const float* vp = Wro_v1 + (part * 32) * VV + wv;
    #pragma unroll 8
    for (int v = 0; v < 32; ++v) acc += hv_l[(part * 32 + v) * 3 + d] * vp[v * VV];
    redB[part * 192 + j] = acc;
  }
  __syncthreads();
  if (t < 192) tv1[t] = redB[t] + redB[192 + t];
  if (t < 256) {  // out_s partials (4-way over f)
    const int o = t & 63, part = t >> 6;
    float acc = 0.f;
    const float* wp = Wro_s2 + (part * 32) * 64 + o;
    #pragma unroll 8
    for (int f = 0; f < 32; ++f) acc += t1[part * 32 + f] * wp[f * 64];
    redA[t] = acc;
  }
  __syncthreads();
  if (t < 64) out[n * 160 + t] = redA[t] + redA[64 + t] + redA[128 + t] + redA[192 + t];
  if (t < 192) {  // out_v partials (2-way over w)
    const int part = t / 96, j = t - part * 96;
    const int w2 = j / 3, d = j - w2 * 3;
    float acc = 0.f;
    const float* vp = Wro_v2 + (part * 32) * 32 + w2;
    #pragma unroll 8
    for (int wv = 0; wv < 32; ++wv) acc += tv1[(part * 32 + wv) * 3 + d] * vp[wv * 32];
    redB[part * 96 + j] = acc;
  }
  __syncthreads();
  if (t < 96) out[n * 160 + 64 + t] = redB[t] + redB[96 + t];
}

// ---------------------------------------------------------------------------
extern "C" void kernel_launch(void* const* d_in, const int* in_sizes, int n_in,
                              void* d_out, int out_size, void* d_ws, size_t ws_size,
                              hipStream_t stream) {
  const float* x      = (const float*)d_in[0];
  const float* embed  = (const float*)d_in[3];
  const float* Wr1    = (const float*)d_in[4];   // [2][1][16]
  const float* Wr2s   = (const float*)d_in[5];   // [2][16][128]
  const float* Wr2v   = (const float*)d_in[6];   // [2][16][64]
  const float* Wsv    = (const float*)d_in[7];   // [2][128][64]
  const float* Wss    = (const float*)d_in[8];   // [2][128][128]
  const float* Wvs    = (const float*)d_in[9];   // [2][64][128]
  const float* Wvv    = (const float*)d_in[10];  // [2][64][64]
  const float* Wro_s1 = (const float*)d_in[11];
  const float* Wro_s2 = (const float*)d_in[12];
  const float* Wro_v1 = (const float*)d_in[13];
  const float* Wro_v2 = (const float*)d_in[14];

  float* ws_f = (float*)d_ws;
  float* hs    = ws_f;                      // 768*128
  float* hsv   = hs + NN * FF;              // 768*64
  float* hv    = hsv + NN * VV;             // 768*192
  float* aggs  = hv + NN * 192;             // 768*128
  float* pvsum = aggs + NN * FF;            // 768*256
  float* Ps    = pvsum + NN * 256;          // 24*768*128
  float* Pv    = Ps + (size_t)SPLITK * NN * FF;   // 24*768*256
  unsigned short* Bs = (unsigned short*)(Pv + (size_t)SPLITK * NN * 256);
  unsigned short* Bv = Bs + (size_t)12288 * 128;
  float* out = (float*)d_out;

  init_kernel<<<NN, 192, 0, stream>>>(embed, Wsv, hs, hsv, hv);

  for (int l = 0; l < 2; ++l) {
    prep_kernel<<<2304, 256, 0, stream>>>(
        hs, hsv, x, Wr2s + l * RH * FF, Wr2v + l * RH * VV, Bs, Bv);
    edge_gemm<<<MB_N * 2 * SPLITK, 256, 0, stream>>>(
        x, Bs, Bv, Wr1 + l * RH, Ps, Pv);
    reduce_kernel<<<(ES4 + EV4) / 256, 256, 0, stream>>>(Ps, Pv, aggs, pvsum);
    node_kernel<<<NN, 512, 0, stream>>>(
        aggs, pvsum, x, Wss + l * FF * FF, Wvs + l * VV * FF, Wvv + l * VV * VV,
        Wsv + ((l + 1) < 2 ? (l + 1) * FF * VV : 0), hs, hsv, hv,
        (l + 1) < 2 ? 1 : 0);
  }

  readout_kernel<<<NN, 512, 0, stream>>>(hs, hv, Wro_s1, Wro_s2, Wro_v1,
                                         Wro_v2, out);
}